// Round 7
// baseline (539.190 us; speedup 1.0000x reference)
//
#include <hip/hip_runtime.h>

// EntNet: B=32, S=256, L=64, D=100, M=20
// K1 encode_k : one row/block contiguous streaming -> LDS stage -> column reduce
// K0 prep_k   : T[d][e] = W[e][d] / keys
// K2 project_k: sWp = enc·W^T, kg = enc·keys^T via T
// K3 entnet_scan: r7 — SIMD CO-RESIDENCY. The ~1400 cyc/step stall is invariant
//    to every single-wave restructure (r0/r1/r3/r5/r6). 64-thr blocks can never
//    put 2 of our 640 waves on one SIMD (blocks spread over 1024 SIMDs first).
//    Fix via block geometry: 512-thread blocks = 8 waves on ONE CU = 2 waves
//    per SIMD. Each wave = unmodified r1 chain (own cbuf slice, no barriers,
//    no inter-wave sharing). Wave A's stalls absorb wave B's issue -> ~2x.
//    __launch_bounds__(512,2) caps regs at 256/wave so both waves fit.

typedef float v2f __attribute__((ext_vector_type(2)));

__global__ __launch_bounds__(320) void encode_k(
    const float* __restrict__ batch,
    const float* __restrict__ encm,
    float* __restrict__ enc)
{
    __shared__ float prod[6400];
    __shared__ float part[200];
    const int t = threadIdx.x;
    const int row = blockIdx.x;       // 8192 blocks
    const float4* rb = (const float4*)batch + (size_t)row * 1600;
    const float4* e4 = (const float4*)encm;
    float4* p4 = (float4*)prod;
    #pragma unroll
    for (int i = 0; i < 5; ++i) {
        const int idx = i * 320 + t;
        float4 x = rb[idx];
        float4 mu = e4[idx];
        float4 p;
        p.x = x.x * mu.x; p.y = x.y * mu.y; p.z = x.z * mu.z; p.w = x.w * mu.w;
        p4[idx] = p;
    }
    __syncthreads();
    if (t < 200) {
        const int c = (t < 100) ? t : (t - 100);
        const int l0 = (t < 100) ? 0 : 32;
        float s0 = 0.f, s1 = 0.f;
        #pragma unroll
        for (int l = 0; l < 32; l += 2) {
            s0 += prod[(l0 + l) * 100 + c];
            s1 += prod[(l0 + l + 1) * 100 + c];
        }
        part[t] = s0 + s1;
    }
    __syncthreads();
    if (t < 100) enc[(size_t)row * 100 + t] = part[t] + part[100 + t];
}

__global__ void prep_k(const float* __restrict__ W,
                       const float* __restrict__ keys,
                       float* __restrict__ T)
{
    const int d = blockIdx.x;
    const int e = threadIdx.x;
    float v = 0.f;
    if (e < 100) v = W[e * 100 + d];
    else if (e < 120) v = keys[(e - 100) * 100 + d];
    T[d * 128 + e] = v;
}

__global__ __launch_bounds__(128) void project_k(
    const float* __restrict__ enc,
    const float* __restrict__ T,
    float* __restrict__ sWp,
    float* __restrict__ kg)
{
    __shared__ float encS[400];
    const int t = threadIdx.x;
    const int row0 = blockIdx.x * 4;
    if (t < 100) ((float4*)encS)[t] = ((const float4*)(enc + (size_t)row0 * 100))[t];
    __syncthreads();
    float a0 = 0.f, a1 = 0.f, a2 = 0.f, a3 = 0.f;
    #pragma unroll 4
    for (int d = 0; d < 100; ++d) {
        const float w = T[d * 128 + t];
        a0 += w * encS[d];
        a1 += w * encS[100 + d];
        a2 += w * encS[200 + d];
        a3 += w * encS[300 + d];
    }
    if (t < 100) {
        sWp[(size_t)row0 * 100 + t]       = a0;
        sWp[(size_t)(row0 + 1) * 100 + t] = a1;
        sWp[(size_t)(row0 + 2) * 100 + t] = a2;
        sWp[(size_t)(row0 + 3) * 100 + t] = a3;
    } else if (t < 120) {
        const int m = t - 100;
        kg[(size_t)row0 * 20 + m]       = a0;
        kg[(size_t)(row0 + 1) * 20 + m] = a1;
        kg[(size_t)(row0 + 2) * 20 + m] = a2;
        kg[(size_t)(row0 + 3) * 20 + m] = a3;
    }
}

template <int CTRL>
__device__ __forceinline__ float dpp_add_f(float x) {
    int s = __builtin_amdgcn_update_dpp(0, __float_as_int(x), CTRL, 0xF, 0xF, true);
    return x + __int_as_float(s);
}
__device__ __forceinline__ float lane63(float x) {
    return __int_as_float(__builtin_amdgcn_readlane(__float_as_int(x), 63));
}
#define DPP6(v) v = dpp_add_f<0x111>(v); v = dpp_add_f<0x112>(v); v = dpp_add_f<0x114>(v); \
                v = dpp_add_f<0x118>(v); v = dpp_add_f<0x142>(v); v = dpp_add_f<0x143>(v);

// Store cand to this wave's cbuf slice: lane -> cbuf[lane] (k=0..63),
// cbuf[64+lane] (k=64..99; lanes 36..63 write the 100..127 pad, never read).
#define CAND_STORE(C0, C1) { cbuf[lane] = (C0); cbuf[64 + lane] = (C1); }

// RES(v2f) = U[e0/e1,:] . cand. 25 uniform ds_read_b128 broadcasts + 100
// v_pk_fma_f32 (natural (k,k+1) pairing: no splat, no op_sel needed).
#define MATVEC_READ(RES)                                                \
    {                                                                   \
        v2f A0 = {0.f, 0.f}, A1 = {0.f, 0.f};                           \
        v2f A2 = {0.f, 0.f}, A3 = {0.f, 0.f};                           \
        _Pragma("unroll")                                               \
        for (int j = 0; j < 25; ++j) {                                  \
            float4 cc = cbuf4[j];                                       \
            v2f clo = {cc.x, cc.y};                                     \
            v2f chi = {cc.z, cc.w};                                     \
            A0 = __builtin_elementwise_fma(UE0[2 * j],     clo, A0);    \
            A1 = __builtin_elementwise_fma(UE0[2 * j + 1], chi, A1);    \
            A2 = __builtin_elementwise_fma(UE1[2 * j],     clo, A2);    \
            A3 = __builtin_elementwise_fma(UE1[2 * j + 1], chi, A3);    \
        }                                                               \
        v2f sA = A0 + A1, sB = A2 + A3;                                 \
        RES.x = sA.x + sA.y;                                            \
        RES.y = sB.x + sB.y;                                            \
    }

__global__ __launch_bounds__(512, 2) void entnet_scan(
    const float* __restrict__ enc,    // [8192*100]
    const float* __restrict__ sWp,    // [8192*100]
    const float* __restrict__ kg,     // [8192*20]
    const float* __restrict__ keys,   // [20*100]
    const float* __restrict__ U,      // [100*100]
    const float* __restrict__ V,      // [100*100]
    const float* __restrict__ paPtr,
    float* __restrict__ out)          // [32*20*100]
{
    __shared__ float cbufAll[8][128]; // one 512B cand slice per wave, no sharing
    const int tid  = threadIdx.x;
    const int lane = tid & 63;
    const int wid  = tid >> 6;        // wave id 0..7 = chain within block
    float* cbuf = cbufAll[wid];
    const float4* cbuf4 = (const float4*)cbuf;
    // 80 blocks: xcd = bid&7 owns b in {4*xcd..4*xcd+3} (80 chains = 10 blocks)
    const int xcd = blockIdx.x & 7;
    const int k8  = blockIdx.x >> 3;          // 0..9
    const int local = k8 * 8 + wid;           // 0..79 within this XCD
    const int b = xcd * 4 + local / 20;
    const int m = local % 20;
    const bool hi = (lane < 36);
    const float h = hi ? 1.f : 0.f;
    const int e0 = lane;
    const int e1 = hi ? (64 + lane) : 99;
    const float pa = paPtr[0];

    // U rows e0/e1 as (k,k+1) v2f pairs: UE0[j] = {U[e0][2j], U[e0][2j+1]}
    v2f UE0[50], UE1[50];
    {
        const float4* u0 = (const float4*)(U + e0 * 100);
        const float4* u1 = (const float4*)(U + e1 * 100);
        #pragma unroll
        for (int k = 0; k < 25; ++k) {
            float4 a = u0[k], c = u1[k];
            UE0[2 * k]     = (v2f){a.x, a.y};
            UE0[2 * k + 1] = (v2f){a.z, a.w};
            UE1[2 * k]     = (v2f){c.x, c.y};
            UE1[2 * k + 1] = (v2f){c.z, c.w};
        }
    }

    float kv0 = 0.f, kv1 = 0.f;
    {
        const float4* km = (const float4*)(keys + m * 100);
        const float4* v0 = (const float4*)(V + e0 * 100);
        const float4* v1 = (const float4*)(V + e1 * 100);
        #pragma unroll
        for (int k = 0; k < 25; ++k) {
            float4 kk = km[k], a = v0[k], c = v1[k];
            kv0 += a.x * kk.x + a.y * kk.y + a.z * kk.z + a.w * kk.w;
            kv1 += c.x * kk.x + c.y * kk.y + c.z * kk.z + c.w * kk.w;
        }
    }
    const float k0 = keys[m * 100 + e0];
    const float k1 = h * keys[m * 100 + e1];
    float nm0 = k0, nm1 = k1;        // unnormalized mem; true mem = rn*nm

    v2f P;                            // P = U . nm (register recurrence)
    CAND_STORE(k0, k1);
    MATVEC_READ(P);

    float nq = k0 * k0 + k1 * k1;     // ||mem_0||^2
    DPP6(nq)
    float nsq = lane63(nq);
    float rn = 1.f;

    const float* encRow = enc + (size_t)b * 25600;
    const float* sWRow  = sWp + (size_t)b * 25600;
    const float* kgRow  = kg + (size_t)b * 5120 + m;

    float sw0 = sWRow[e0], sw1 = sWRow[e1];
    float g;
    {
        const float sv0 = encRow[e0], sv1 = encRow[e1];
        const float kg0 = kgRow[0];
        float q1 = sv0 * nm0 + sv1 * nm1;
        DPP6(q1)
        const float Q1 = lane63(q1);
        g = 1.f / (1.f + __expf(-(Q1 + kg0)));   // rn == 1 at t=0
    }

    for (int step = 0; step < 256; ++step) {
        const int nxt = (step < 255 ? step + 1 : 255);
        const float nsv0 = encRow[nxt * 100 + e0], nsv1 = encRow[nxt * 100 + e1];
        const float nsw0 = sWRow[nxt * 100 + e0], nsw1 = sWRow[nxt * 100 + e1];
        const float nkg  = kgRow[nxt * 20];

        // critical path: P -> x -> cand -> LDS round-trip matvec -> P'
        const float x0 = rn * P.x + kv0 + sw0;
        const float x1 = rn * P.y + kv1 + sw1;
        float c0 = (x0 >= 0.f) ? x0 : pa * x0;
        float c1 = (x1 >= 0.f) ? x1 : pa * x1;
        c1 *= h;

        CAND_STORE(c0, c1);           // issue early: LDS latency hides under DPP

        // off-path norm partials (overlap LDS round-trip)
        float q3 = nm0 * c0 + nm1 * c1;             // nm . cand
        float p4 = c0 * c0 + c1 * c1;               // cand . cand
        #define RND2(C) q3 = dpp_add_f<C>(q3); p4 = dpp_add_f<C>(p4);
        RND2(0x111) RND2(0x112) RND2(0x114) RND2(0x118) RND2(0x142) RND2(0x143)
        #undef RND2

        v2f Q;
        MATVEC_READ(Q);

        const float Q3 = lane63(q3);
        const float P4 = lane63(p4);
        const float n2 = nsq + 2.f * (g * rn) * Q3 + g * g * P4;
        const float rnn = rsqrtf(n2);               // rn_{t+1}
        nsq = 1.f;

        nm0 = rn * nm0 + g * c0;
        nm1 = rn * nm1 + g * c1;
        P.x = rn * P.x + g * Q.x;
        P.y = rn * P.y + g * Q.y;

        // gate for step t+1 (overlaps next iteration's front)
        float q1 = nsv0 * nm0 + nsv1 * nm1;
        DPP6(q1)
        const float Q1 = lane63(q1);
        g = 1.f / (1.f + __expf(-(rnn * Q1 + nkg)));

        rn = rnn;
        sw0 = nsw0; sw1 = nsw1;
    }
    float* orow = out + (size_t)(b * 20 + m) * 100;
    orow[e0] = nm0 * rn;
    if (hi) orow[e1] = nm1 * rn;
}

extern "C" void kernel_launch(void* const* d_in, const int* in_sizes, int n_in,
                              void* d_out, int out_size, void* d_ws, size_t ws_size,
                              hipStream_t stream) {
    const float* batch = (const float*)d_in[0];
    const float* encm  = (const float*)d_in[1];
    const float* keys  = (const float*)d_in[2];
    const float* U     = (const float*)d_in[3];
    const float* V     = (const float*)d_in[4];
    const float* W     = (const float*)d_in[5];
    const float* pa    = (const float*)d_in[6];
    float* out = (float*)d_out;

    float* enc = (float*)d_ws;          // 819200 floats
    float* sWp = enc + 819200;          // 819200 floats
    float* kgb = sWp + 819200;          // 163840 floats
    float* T   = kgb + 163840;          // 12800 floats

    encode_k<<<8192, 320, 0, stream>>>(batch, encm, enc);
    prep_k<<<100, 128, 0, stream>>>(W, keys, T);
    project_k<<<2048, 128, 0, stream>>>(enc, T, sWp, kgb);
    entnet_scan<<<80, 512, 0, stream>>>(enc, sWp, kgb, keys, U, V, pa, out);
}

// Round 9
// 509.789 us; speedup vs baseline: 1.0577x; 1.0577x over previous
//
#include <hip/hip_runtime.h>

// EntNet: B=32, S=256, L=64, D=100, M=20
// r8/r9: FUSE the preprocessing. Non-scan time was a constant ~287 µs across
// r0-r6 (total - scan) for ~45 µs of roofline work — bigger than the scan.
// encode_project_k: one block per (b,s) row: stage batch*encm in LDS ->
// column-reduce to enc row (kept in LDS) -> dot against W rows (sWp) and
// keys rows (kg) in-place. Kills prep_k, project_k, the T matrix, and an
// enc round-trip. 2 launches total.
// entnet_scan: proven r1 body (202 µs): 640 chains, 1 wave, LDS cand
// broadcast + v_pk_fma matvec. (r7 showed co-residency only adds contention;
// total time == single-chain step latency.)
// (Round 8 was an infra failure — container acquisition; identical rerun.)

typedef float v2f __attribute__((ext_vector_type(2)));

__global__ __launch_bounds__(320) void encode_project_k(
    const float* __restrict__ batch,
    const float* __restrict__ encm,
    const float* __restrict__ W,
    const float* __restrict__ keys,
    float* __restrict__ enc,
    float* __restrict__ sWp,
    float* __restrict__ kg)
{
    __shared__ float prod[6400];
    __shared__ __align__(16) float part[200];
    const int t = threadIdx.x;
    const int row = blockIdx.x;       // 8192 blocks: row = b*256 + s
    // phase 1: stage batch_row * encm products (contiguous float4 stream)
    const float4* rb = (const float4*)batch + (size_t)row * 1600;
    const float4* e4 = (const float4*)encm;
    float4* p4 = (float4*)prod;
    #pragma unroll
    for (int i = 0; i < 5; ++i) {
        const int idx = i * 320 + t;
        float4 x = rb[idx];
        float4 mu = e4[idx];
        float4 p;
        p.x = x.x * mu.x; p.y = x.y * mu.y; p.z = x.z * mu.z; p.w = x.w * mu.w;
        p4[idx] = p;
    }
    __syncthreads();
    // phase 2: column reduce over L=64 words
    if (t < 200) {
        const int c = (t < 100) ? t : (t - 100);
        const int l0 = (t < 100) ? 0 : 32;
        float s0 = 0.f, s1 = 0.f;
        #pragma unroll
        for (int l = 0; l < 32; l += 2) {
            s0 += prod[(l0 + l) * 100 + c];
            s1 += prod[(l0 + l + 1) * 100 + c];
        }
        part[t] = s0 + s1;
    }
    __syncthreads();
    if (t < 100) {
        const float v = part[t] + part[100 + t];
        part[t] = v;                      // enc row stays in LDS for phase 3
        enc[(size_t)row * 100 + t] = v;
    }
    __syncthreads();
    // phase 3: project. Thread t<100 -> sWp[row][t] = enc_row . W[t,:]
    //          thread 100..119      -> kg[row][t-100] = enc_row . keys[t-100,:]
    // Branch-free loop: per-thread row pointer; W/keys are L2-hot (40KB/8KB).
    if (t < 120) {
        const float* mrow = (t < 100) ? (W + t * 100) : (keys + (t - 100) * 100);
        const float4* m4 = (const float4*)mrow;
        const float4* s4 = (const float4*)part;
        float a0 = 0.f, a1 = 0.f, a2 = 0.f, a3 = 0.f;
        #pragma unroll
        for (int k = 0; k < 24; k += 4) {
            float4 w0 = m4[k],     e0 = s4[k];
            float4 w1 = m4[k + 1], e1 = s4[k + 1];
            float4 w2 = m4[k + 2], e2 = s4[k + 2];
            float4 w3 = m4[k + 3], e3 = s4[k + 3];
            a0 += w0.x * e0.x + w0.y * e0.y + w0.z * e0.z + w0.w * e0.w;
            a1 += w1.x * e1.x + w1.y * e1.y + w1.z * e1.z + w1.w * e1.w;
            a2 += w2.x * e2.x + w2.y * e2.y + w2.z * e2.z + w2.w * e2.w;
            a3 += w3.x * e3.x + w3.y * e3.y + w3.z * e3.z + w3.w * e3.w;
        }
        {   // k = 24 tail
            float4 w0 = m4[24], e0 = s4[24];
            a0 += w0.x * e0.x + w0.y * e0.y + w0.z * e0.z + w0.w * e0.w;
        }
        const float acc = (a0 + a1) + (a2 + a3);
        if (t < 100) sWp[(size_t)row * 100 + t] = acc;
        else         kg[(size_t)row * 20 + (t - 100)] = acc;
    }
}

template <int CTRL>
__device__ __forceinline__ float dpp_add_f(float x) {
    int s = __builtin_amdgcn_update_dpp(0, __float_as_int(x), CTRL, 0xF, 0xF, true);
    return x + __int_as_float(s);
}
__device__ __forceinline__ float lane63(float x) {
    return __int_as_float(__builtin_amdgcn_readlane(__float_as_int(x), 63));
}
#define DPP6(v) v = dpp_add_f<0x111>(v); v = dpp_add_f<0x112>(v); v = dpp_add_f<0x114>(v); \
                v = dpp_add_f<0x118>(v); v = dpp_add_f<0x142>(v); v = dpp_add_f<0x143>(v);

// Store cand to LDS: lane -> cbuf[lane] (k=0..63), cbuf[64+lane] (k=64..99;
// lanes 36..63 write the 100..127 pad, never read).
#define CAND_STORE(C0, C1) { cbuf[lane] = (C0); cbuf[64 + lane] = (C1); }

// RES(v2f) = U[e0/e1,:] . cand. 25 uniform ds_read_b128 broadcasts + 100
// v_pk_fma_f32 (natural (k,k+1) pairing: no splat, no op_sel needed).
#define MATVEC_READ(RES)                                                \
    {                                                                   \
        v2f A0 = {0.f, 0.f}, A1 = {0.f, 0.f};                           \
        v2f A2 = {0.f, 0.f}, A3 = {0.f, 0.f};                           \
        _Pragma("unroll")                                               \
        for (int j = 0; j < 25; ++j) {                                  \
            float4 cc = cbuf4[j];                                       \
            v2f clo = {cc.x, cc.y};                                     \
            v2f chi = {cc.z, cc.w};                                     \
            A0 = __builtin_elementwise_fma(UE0[2 * j],     clo, A0);    \
            A1 = __builtin_elementwise_fma(UE0[2 * j + 1], chi, A1);    \
            A2 = __builtin_elementwise_fma(UE1[2 * j],     clo, A2);    \
            A3 = __builtin_elementwise_fma(UE1[2 * j + 1], chi, A3);    \
        }                                                               \
        v2f sA = A0 + A1, sB = A2 + A3;                                 \
        RES.x = sA.x + sA.y;                                            \
        RES.y = sB.x + sB.y;                                            \
    }

__global__ __attribute__((amdgpu_waves_per_eu(1, 1))) __launch_bounds__(64)
void entnet_scan(
    const float* __restrict__ enc,    // [8192*100]
    const float* __restrict__ sWp,    // [8192*100]
    const float* __restrict__ kg,     // [8192*20]
    const float* __restrict__ keys,   // [20*100]
    const float* __restrict__ U,      // [100*100]
    const float* __restrict__ V,      // [100*100]
    const float* __restrict__ paPtr,
    float* __restrict__ out)          // [32*20*100]
{
    __shared__ float4 cbuf4[32];      // 128 floats: cand broadcast buffer
    float* cbuf = (float*)cbuf4;
    const int lane = threadIdx.x;
    // XCD swizzle: XCD = blockIdx%8 serves b in {4*xcd .. 4*xcd+3}
    const int xcd = blockIdx.x & 7;
    const int gg  = blockIdx.x >> 3;          // 0..79
    const int b = xcd * 4 + gg / 20;
    const int m = gg % 20;
    const bool hi = (lane < 36);
    const float h = hi ? 1.f : 0.f;
    const int e0 = lane;
    const int e1 = hi ? (64 + lane) : 99;
    const float pa = paPtr[0];

    // U rows e0/e1 as (k,k+1) v2f pairs: UE0[j] = {U[e0][2j], U[e0][2j+1]}
    v2f UE0[50], UE1[50];
    {
        const float4* u0 = (const float4*)(U + e0 * 100);
        const float4* u1 = (const float4*)(U + e1 * 100);
        #pragma unroll
        for (int k = 0; k < 25; ++k) {
            float4 a = u0[k], c = u1[k];
            UE0[2 * k]     = (v2f){a.x, a.y};
            UE0[2 * k + 1] = (v2f){a.z, a.w};
            UE1[2 * k]     = (v2f){c.x, c.y};
            UE1[2 * k + 1] = (v2f){c.z, c.w};
        }
    }

    float kv0 = 0.f, kv1 = 0.f;
    {
        const float4* km = (const float4*)(keys + m * 100);
        const float4* v0 = (const float4*)(V + e0 * 100);
        const float4* v1 = (const float4*)(V + e1 * 100);
        #pragma unroll
        for (int k = 0; k < 25; ++k) {
            float4 kk = km[k], a = v0[k], c = v1[k];
            kv0 += a.x * kk.x + a.y * kk.y + a.z * kk.z + a.w * kk.w;
            kv1 += c.x * kk.x + c.y * kk.y + c.z * kk.z + c.w * kk.w;
        }
    }
    const float k0 = keys[m * 100 + e0];
    const float k1 = h * keys[m * 100 + e1];
    float nm0 = k0, nm1 = k1;        // unnormalized mem; true mem = rn*nm

    v2f P;                            // P = U . nm (register recurrence)
    CAND_STORE(k0, k1);
    MATVEC_READ(P);

    float nq = k0 * k0 + k1 * k1;     // ||mem_0||^2
    DPP6(nq)
    float nsq = lane63(nq);
    float rn = 1.f;

    const float* encRow = enc + (size_t)b * 25600;
    const float* sWRow  = sWp + (size_t)b * 25600;
    const float* kgRow  = kg + (size_t)b * 5120 + m;

    float sw0 = sWRow[e0], sw1 = sWRow[e1];
    float g;
    {
        const float sv0 = encRow[e0], sv1 = encRow[e1];
        const float kg0 = kgRow[0];
        float q1 = sv0 * nm0 + sv1 * nm1;
        DPP6(q1)
        const float Q1 = lane63(q1);
        g = 1.f / (1.f + __expf(-(Q1 + kg0)));   // rn == 1 at t=0
    }

    for (int step = 0; step < 256; ++step) {
        const int nxt = (step < 255 ? step + 1 : 255);
        const float nsv0 = encRow[nxt * 100 + e0], nsv1 = encRow[nxt * 100 + e1];
        const float nsw0 = sWRow[nxt * 100 + e0], nsw1 = sWRow[nxt * 100 + e1];
        const float nkg  = kgRow[nxt * 20];

        // critical path: P -> x -> cand -> LDS round-trip matvec -> P'
        const float x0 = rn * P.x + kv0 + sw0;
        const float x1 = rn * P.y + kv1 + sw1;
        float c0 = (x0 >= 0.f) ? x0 : pa * x0;
        float c1 = (x1 >= 0.f) ? x1 : pa * x1;
        c1 *= h;

        CAND_STORE(c0, c1);           // issue early: LDS latency hides under DPP

        // off-path norm partials (overlap LDS round-trip)
        float q3 = nm0 * c0 + nm1 * c1;             // nm . cand
        float p4 = c0 * c0 + c1 * c1;               // cand . cand
        #define RND2(C) q3 = dpp_add_f<C>(q3); p4 = dpp_add_f<C>(p4);
        RND2(0x111) RND2(0x112) RND2(0x114) RND2(0x118) RND2(0x142) RND2(0x143)
        #undef RND2

        v2f Q;
        MATVEC_READ(Q);

        const float Q3 = lane63(q3);
        const float P4 = lane63(p4);
        const float n2 = nsq + 2.f * (g * rn) * Q3 + g * g * P4;
        const float rnn = rsqrtf(n2);               // rn_{t+1}
        nsq = 1.f;

        nm0 = rn * nm0 + g * c0;
        nm1 = rn * nm1 + g * c1;
        P.x = rn * P.x + g * Q.x;
        P.y = rn * P.y + g * Q.y;

        // gate for step t+1 (overlaps next iteration's front)
        float q1 = nsv0 * nm0 + nsv1 * nm1;
        DPP6(q1)
        const float Q1 = lane63(q1);
        g = 1.f / (1.f + __expf(-(rnn * Q1 + nkg)));

        rn = rnn;
        sw0 = nsw0; sw1 = nsw1;
    }
    float* orow = out + (size_t)(b * 20 + m) * 100;
    orow[e0] = nm0 * rn;
    if (hi) orow[e1] = nm1 * rn;
}

extern "C" void kernel_launch(void* const* d_in, const int* in_sizes, int n_in,
                              void* d_out, int out_size, void* d_ws, size_t ws_size,
                              hipStream_t stream) {
    const float* batch = (const float*)d_in[0];
    const float* encm  = (const float*)d_in[1];
    const float* keys  = (const float*)d_in[2];
    const float* U     = (const float*)d_in[3];
    const float* V     = (const float*)d_in[4];
    const float* W     = (const float*)d_in[5];
    const float* pa    = (const float*)d_in[6];
    float* out = (float*)d_out;

    float* enc = (float*)d_ws;          // 819200 floats
    float* sWp = enc + 819200;          // 819200 floats
    float* kgb = sWp + 819200;          // 163840 floats

    encode_project_k<<<8192, 320, 0, stream>>>(batch, encm, W, keys, enc, sWp, kgb);
    entnet_scan<<<640, 64, 0, stream>>>(enc, sWp, kgb, keys, U, V, pa, out);
}

// Round 10
// 501.746 us; speedup vs baseline: 1.0746x; 1.0160x over previous
//
#include <hip/hip_runtime.h>

// EntNet: B=32, S=256, L=64, D=100, M=20
// r10: revert to the proven r6 4-kernel pipeline (fusion cost +21 µs: phase-3
// W-traffic 4x'd). Scan change: the ~1400 stall cy/step is theorized to be
// MATVEC read-batch serialization (25 ds_read_b128 need 100 VGPRs; at
// VGPR_Count=140 the compiler emits ~5 batches each paying full LDS latency).
// Fix: MATVEC_LOADS = 25 named float4 locals (all reads issued together),
// DPP norm tree between loads and fmas (covers last-read latency),
// MATVEC_FMAS with 8 accumulator chains (shorter dep tail).
// VGPR_Count >= 200 is the diagnostic that the hoist happened.

typedef float v2f __attribute__((ext_vector_type(2)));

__global__ __launch_bounds__(320) void encode_k(
    const float* __restrict__ batch,
    const float* __restrict__ encm,
    float* __restrict__ enc)
{
    __shared__ float prod[6400];
    __shared__ float part[200];
    const int t = threadIdx.x;
    const int row = blockIdx.x;       // 8192 blocks
    const float4* rb = (const float4*)batch + (size_t)row * 1600;
    const float4* e4 = (const float4*)encm;
    float4* p4 = (float4*)prod;
    #pragma unroll
    for (int i = 0; i < 5; ++i) {
        const int idx = i * 320 + t;
        float4 x = rb[idx];
        float4 mu = e4[idx];
        float4 p;
        p.x = x.x * mu.x; p.y = x.y * mu.y; p.z = x.z * mu.z; p.w = x.w * mu.w;
        p4[idx] = p;
    }
    __syncthreads();
    if (t < 200) {
        const int c = (t < 100) ? t : (t - 100);
        const int l0 = (t < 100) ? 0 : 32;
        float s0 = 0.f, s1 = 0.f;
        #pragma unroll
        for (int l = 0; l < 32; l += 2) {
            s0 += prod[(l0 + l) * 100 + c];
            s1 += prod[(l0 + l + 1) * 100 + c];
        }
        part[t] = s0 + s1;
    }
    __syncthreads();
    if (t < 100) enc[(size_t)row * 100 + t] = part[t] + part[100 + t];
}

__global__ void prep_k(const float* __restrict__ W,
                       const float* __restrict__ keys,
                       float* __restrict__ T)
{
    const int d = blockIdx.x;
    const int e = threadIdx.x;
    float v = 0.f;
    if (e < 100) v = W[e * 100 + d];
    else if (e < 120) v = keys[(e - 100) * 100 + d];
    T[d * 128 + e] = v;
}

__global__ __launch_bounds__(128) void project_k(
    const float* __restrict__ enc,
    const float* __restrict__ T,
    float* __restrict__ sWp,
    float* __restrict__ kg)
{
    __shared__ float encS[400];
    const int t = threadIdx.x;
    const int row0 = blockIdx.x * 4;
    if (t < 100) ((float4*)encS)[t] = ((const float4*)(enc + (size_t)row0 * 100))[t];
    __syncthreads();
    float a0 = 0.f, a1 = 0.f, a2 = 0.f, a3 = 0.f;
    #pragma unroll 4
    for (int d = 0; d < 100; ++d) {
        const float w = T[d * 128 + t];
        a0 += w * encS[d];
        a1 += w * encS[100 + d];
        a2 += w * encS[200 + d];
        a3 += w * encS[300 + d];
    }
    if (t < 100) {
        sWp[(size_t)row0 * 100 + t]       = a0;
        sWp[(size_t)(row0 + 1) * 100 + t] = a1;
        sWp[(size_t)(row0 + 2) * 100 + t] = a2;
        sWp[(size_t)(row0 + 3) * 100 + t] = a3;
    } else if (t < 120) {
        const int m = t - 100;
        kg[(size_t)row0 * 20 + m]       = a0;
        kg[(size_t)(row0 + 1) * 20 + m] = a1;
        kg[(size_t)(row0 + 2) * 20 + m] = a2;
        kg[(size_t)(row0 + 3) * 20 + m] = a3;
    }
}

template <int CTRL>
__device__ __forceinline__ float dpp_add_f(float x) {
    int s = __builtin_amdgcn_update_dpp(0, __float_as_int(x), CTRL, 0xF, 0xF, true);
    return x + __int_as_float(s);
}
__device__ __forceinline__ float lane63(float x) {
    return __int_as_float(__builtin_amdgcn_readlane(__float_as_int(x), 63));
}
#define DPP6(v) v = dpp_add_f<0x111>(v); v = dpp_add_f<0x112>(v); v = dpp_add_f<0x114>(v); \
                v = dpp_add_f<0x118>(v); v = dpp_add_f<0x142>(v); v = dpp_add_f<0x143>(v);

// Store cand to LDS: lane -> cbuf[lane] (k=0..63), cbuf[64+lane] (k=64..99;
// lanes 36..63 write the 100..127 pad, never read).
#define CAND_STORE(C0, C1) { cbuf[lane] = (C0); cbuf[64 + lane] = (C1); }

// All 25 broadcast reads issued together into named locals (100 VGPRs) so the
// compiler emits one back-to-back ds_read_b128 stream instead of ~5 batches
// each paying full LDS latency.
#define MATVEC_LOADS \
    float4 L00=cbuf4[0], L01=cbuf4[1], L02=cbuf4[2], L03=cbuf4[3], L04=cbuf4[4], \
           L05=cbuf4[5], L06=cbuf4[6], L07=cbuf4[7], L08=cbuf4[8], L09=cbuf4[9], \
           L10=cbuf4[10],L11=cbuf4[11],L12=cbuf4[12],L13=cbuf4[13],L14=cbuf4[14], \
           L15=cbuf4[15],L16=cbuf4[16],L17=cbuf4[17],L18=cbuf4[18],L19=cbuf4[19], \
           L20=cbuf4[20],L21=cbuf4[21],L22=cbuf4[22],L23=cbuf4[23],L24=cbuf4[24];

// Even j -> chains A0..A3, odd j -> A4..A7 (dep tail 13 instead of 25).
#define MVF_E(J, LV) { v2f lo={LV.x,LV.y}, hv={LV.z,LV.w}; \
    A0=__builtin_elementwise_fma(UE0[2*(J)],  lo,A0); \
    A1=__builtin_elementwise_fma(UE0[2*(J)+1],hv,A1); \
    A2=__builtin_elementwise_fma(UE1[2*(J)],  lo,A2); \
    A3=__builtin_elementwise_fma(UE1[2*(J)+1],hv,A3); }
#define MVF_O(J, LV) { v2f lo={LV.x,LV.y}, hv={LV.z,LV.w}; \
    A4=__builtin_elementwise_fma(UE0[2*(J)],  lo,A4); \
    A5=__builtin_elementwise_fma(UE0[2*(J)+1],hv,A5); \
    A6=__builtin_elementwise_fma(UE1[2*(J)],  lo,A6); \
    A7=__builtin_elementwise_fma(UE1[2*(J)+1],hv,A7); }

#define MATVEC_FMAS(RES) { \
    v2f A0={0.f,0.f},A1={0.f,0.f},A2={0.f,0.f},A3={0.f,0.f}; \
    v2f A4={0.f,0.f},A5={0.f,0.f},A6={0.f,0.f},A7={0.f,0.f}; \
    MVF_E(0,L00)  MVF_O(1,L01)  MVF_E(2,L02)  MVF_O(3,L03)  MVF_E(4,L04) \
    MVF_O(5,L05)  MVF_E(6,L06)  MVF_O(7,L07)  MVF_E(8,L08)  MVF_O(9,L09) \
    MVF_E(10,L10) MVF_O(11,L11) MVF_E(12,L12) MVF_O(13,L13) MVF_E(14,L14) \
    MVF_O(15,L15) MVF_E(16,L16) MVF_O(17,L17) MVF_E(18,L18) MVF_O(19,L19) \
    MVF_E(20,L20) MVF_O(21,L21) MVF_E(22,L22) MVF_O(23,L23) MVF_E(24,L24) \
    v2f sx = (A0 + A4) + (A1 + A5); \
    v2f sy = (A2 + A6) + (A3 + A7); \
    RES.x = sx.x + sx.y; \
    RES.y = sy.x + sy.y; }

__global__ __attribute__((amdgpu_waves_per_eu(1, 1))) __launch_bounds__(64)
void entnet_scan(
    const float* __restrict__ enc,    // [8192*100]
    const float* __restrict__ sWp,    // [8192*100]
    const float* __restrict__ kg,     // [8192*20]
    const float* __restrict__ keys,   // [20*100]
    const float* __restrict__ U,      // [100*100]
    const float* __restrict__ V,      // [100*100]
    const float* __restrict__ paPtr,
    float* __restrict__ out)          // [32*20*100]
{
    __shared__ float4 cbuf4[32];      // 128 floats: cand broadcast buffer
    float* cbuf = (float*)cbuf4;
    const int lane = threadIdx.x;
    // XCD swizzle: XCD = blockIdx%8 serves b in {4*xcd .. 4*xcd+3}
    const int xcd = blockIdx.x & 7;
    const int gg  = blockIdx.x >> 3;          // 0..79
    const int b = xcd * 4 + gg / 20;
    const int m = gg % 20;
    const bool hi = (lane < 36);
    const float h = hi ? 1.f : 0.f;
    const int e0 = lane;
    const int e1 = hi ? (64 + lane) : 99;
    const float pa = paPtr[0];

    // U rows e0/e1 as (k,k+1) v2f pairs: UE0[j] = {U[e0][2j], U[e0][2j+1]}
    v2f UE0[50], UE1[50];
    {
        const float4* u0 = (const float4*)(U + e0 * 100);
        const float4* u1 = (const float4*)(U + e1 * 100);
        #pragma unroll
        for (int k = 0; k < 25; ++k) {
            float4 a = u0[k], c = u1[k];
            UE0[2 * k]     = (v2f){a.x, a.y};
            UE0[2 * k + 1] = (v2f){a.z, a.w};
            UE1[2 * k]     = (v2f){c.x, c.y};
            UE1[2 * k + 1] = (v2f){c.z, c.w};
        }
    }

    float kv0 = 0.f, kv1 = 0.f;
    {
        const float4* km = (const float4*)(keys + m * 100);
        const float4* v0 = (const float4*)(V + e0 * 100);
        const float4* v1 = (const float4*)(V + e1 * 100);
        #pragma unroll
        for (int k = 0; k < 25; ++k) {
            float4 kk = km[k], a = v0[k], c = v1[k];
            kv0 += a.x * kk.x + a.y * kk.y + a.z * kk.z + a.w * kk.w;
            kv1 += c.x * kk.x + c.y * kk.y + c.z * kk.z + c.w * kk.w;
        }
    }
    const float k0 = keys[m * 100 + e0];
    const float k1 = h * keys[m * 100 + e1];
    float nm0 = k0, nm1 = k1;        // unnormalized mem; true mem = rn*nm

    v2f P;                            // P = U . nm (register recurrence)
    CAND_STORE(k0, k1);
    {
        MATVEC_LOADS
        MATVEC_FMAS(P)
    }

    float nq = k0 * k0 + k1 * k1;     // ||mem_0||^2
    DPP6(nq)
    float nsq = lane63(nq);
    float rn = 1.f;

    const float* encRow = enc + (size_t)b * 25600;
    const float* sWRow  = sWp + (size_t)b * 25600;
    const float* kgRow  = kg + (size_t)b * 5120 + m;

    float sw0 = sWRow[e0], sw1 = sWRow[e1];
    float g;
    {
        const float sv0 = encRow[e0], sv1 = encRow[e1];
        const float kg0 = kgRow[0];
        float q1 = sv0 * nm0 + sv1 * nm1;
        DPP6(q1)
        const float Q1 = lane63(q1);
        g = 1.f / (1.f + __expf(-(Q1 + kg0)));   // rn == 1 at t=0
    }

    for (int step = 0; step < 256; ++step) {
        const int nxt = (step < 255 ? step + 1 : 255);
        const float nsv0 = encRow[nxt * 100 + e0], nsv1 = encRow[nxt * 100 + e1];
        const float nsw0 = sWRow[nxt * 100 + e0], nsw1 = sWRow[nxt * 100 + e1];
        const float nkg  = kgRow[nxt * 20];

        // critical path: P -> x -> cand -> LDS round-trip matvec -> P'
        const float x0 = rn * P.x + kv0 + sw0;
        const float x1 = rn * P.y + kv1 + sw1;
        float c0 = (x0 >= 0.f) ? x0 : pa * x0;
        float c1 = (x1 >= 0.f) ? x1 : pa * x1;
        c1 *= h;

        CAND_STORE(c0, c1);           // stores first (in-order LDS per wave)

        MATVEC_LOADS                  // 25 ds_read_b128 issued back-to-back

        // independent DPP work placed between loads and consumers: covers the
        // last read's latency
        float q3 = nm0 * c0 + nm1 * c1;             // nm . cand
        float p4 = c0 * c0 + c1 * c1;               // cand . cand
        #define RND2(C) q3 = dpp_add_f<C>(q3); p4 = dpp_add_f<C>(p4);
        RND2(0x111) RND2(0x112) RND2(0x114) RND2(0x118) RND2(0x142) RND2(0x143)
        #undef RND2

        v2f Q;
        MATVEC_FMAS(Q)

        const float Q3 = lane63(q3);
        const float P4 = lane63(p4);
        const float n2 = nsq + 2.f * (g * rn) * Q3 + g * g * P4;
        const float rnn = rsqrtf(n2);               // rn_{t+1}
        nsq = 1.f;

        nm0 = rn * nm0 + g * c0;
        nm1 = rn * nm1 + g * c1;
        P.x = rn * P.x + g * Q.x;
        P.y = rn * P.y + g * Q.y;

        // gate for step t+1 (overlaps next iteration's front)
        float q1 = nsv0 * nm0 + nsv1 * nm1;
        DPP6(q1)
        const float Q1 = lane63(q1);
        g = 1.f / (1.f + __expf(-(rnn * Q1 + nkg)));

        rn = rnn;
        sw0 = nsw0; sw1 = nsw1;
    }
    float* orow = out + (size_t)(b * 20 + m) * 100;
    orow[e0] = nm0 * rn;
    if (hi) orow[e1] = nm1 * rn;
}

extern "C" void kernel_launch(void* const* d_in, const int* in_sizes, int n_in,
                              void* d_out, int out_size, void* d_ws, size_t ws_size,
                              hipStream_t stream) {
    const float* batch = (const float*)d_in[0];
    const float* encm  = (const float*)d_in[1];
    const float* keys  = (const float*)d_in[2];
    const float* U     = (const float*)d_in[3];
    const float* V     = (const float*)d_in[4];
    const float* W     = (const float*)d_in[5];
    const float* pa    = (const float*)d_in[6];
    float* out = (float*)d_out;

    float* enc = (float*)d_ws;          // 819200 floats
    float* sWp = enc + 819200;          // 819200 floats
    float* kgb = sWp + 819200;          // 163840 floats
    float* T   = kgb + 163840;          // 12800 floats

    encode_k<<<8192, 320, 0, stream>>>(batch, encm, enc);
    prep_k<<<100, 128, 0, stream>>>(W, keys, T);
    project_k<<<2048, 128, 0, stream>>>(enc, T, sWp, kgb);
    entnet_scan<<<640, 64, 0, stream>>>(enc, sWp, kgb, keys, U, V, pa, out);
}

// Round 11
// 499.429 us; speedup vs baseline: 1.0796x; 1.0046x over previous
//
#include <hip/hip_runtime.h>

// EntNet: B=32, S=256, L=64, D=100, M=20
// r11: single variable = encode_k rewritten LDS-free. Old encode staged
// 6400 floats in LDS (26 KB, 2 barriers, 6 blocks/CU cap, 100/320-thread
// tail). New: thread owns one (row, float2-col); 64 independent coalesced
// 8B loads; encm (25.6 KB) is L1-resident. Minimal BW-bound form (~34 µs
// roofline). prep/project/scan byte-identical to r6 best (487.9 µs), so
// delta(total) == delta(encode). Scan = proven r1 body, 202 µs latency wall
// (8 structural attacks failed: r0/1/2/3/5/6/7/10).

typedef float v2f __attribute__((ext_vector_type(2)));

__global__ __launch_bounds__(256) void encode_k(
    const float* __restrict__ batch,
    const float* __restrict__ encm,
    float* __restrict__ enc)
{
    const int gt = blockIdx.x * 256 + threadIdx.x;   // 1600 blocks, exact
    const int row = gt / 50;                          // 0..8191
    const int c2  = gt - row * 50;                    // float2 column 0..49
    const float2* b2 = (const float2*)batch + (size_t)row * 3200 + c2;
    const float2* e2 = (const float2*)encm + c2;
    float s0 = 0.f, s1 = 0.f;
    #pragma unroll 8
    for (int l = 0; l < 64; ++l) {
        const float2 x = b2[l * 50];
        const float2 m = e2[l * 50];
        s0 = __builtin_fmaf(x.x, m.x, s0);
        s1 = __builtin_fmaf(x.y, m.y, s1);
    }
    float2 r; r.x = s0; r.y = s1;
    ((float2*)enc)[gt] = r;
}

__global__ void prep_k(const float* __restrict__ W,
                       const float* __restrict__ keys,
                       float* __restrict__ T)
{
    const int d = blockIdx.x;
    const int e = threadIdx.x;
    float v = 0.f;
    if (e < 100) v = W[e * 100 + d];
    else if (e < 120) v = keys[(e - 100) * 100 + d];
    T[d * 128 + e] = v;
}

__global__ __launch_bounds__(128) void project_k(
    const float* __restrict__ enc,
    const float* __restrict__ T,
    float* __restrict__ sWp,
    float* __restrict__ kg)
{
    __shared__ float encS[400];
    const int t = threadIdx.x;
    const int row0 = blockIdx.x * 4;
    if (t < 100) ((float4*)encS)[t] = ((const float4*)(enc + (size_t)row0 * 100))[t];
    __syncthreads();
    float a0 = 0.f, a1 = 0.f, a2 = 0.f, a3 = 0.f;
    #pragma unroll 4
    for (int d = 0; d < 100; ++d) {
        const float w = T[d * 128 + t];
        a0 += w * encS[d];
        a1 += w * encS[100 + d];
        a2 += w * encS[200 + d];
        a3 += w * encS[300 + d];
    }
    if (t < 100) {
        sWp[(size_t)row0 * 100 + t]       = a0;
        sWp[(size_t)(row0 + 1) * 100 + t] = a1;
        sWp[(size_t)(row0 + 2) * 100 + t] = a2;
        sWp[(size_t)(row0 + 3) * 100 + t] = a3;
    } else if (t < 120) {
        const int m = t - 100;
        kg[(size_t)row0 * 20 + m]       = a0;
        kg[(size_t)(row0 + 1) * 20 + m] = a1;
        kg[(size_t)(row0 + 2) * 20 + m] = a2;
        kg[(size_t)(row0 + 3) * 20 + m] = a3;
    }
}

template <int CTRL>
__device__ __forceinline__ float dpp_add_f(float x) {
    int s = __builtin_amdgcn_update_dpp(0, __float_as_int(x), CTRL, 0xF, 0xF, true);
    return x + __int_as_float(s);
}
__device__ __forceinline__ float lane63(float x) {
    return __int_as_float(__builtin_amdgcn_readlane(__float_as_int(x), 63));
}
#define DPP6(v) v = dpp_add_f<0x111>(v); v = dpp_add_f<0x112>(v); v = dpp_add_f<0x114>(v); \
                v = dpp_add_f<0x118>(v); v = dpp_add_f<0x142>(v); v = dpp_add_f<0x143>(v);

// Store cand to LDS: lane -> cbuf[lane] (k=0..63), cbuf[64+lane] (k=64..99;
// lanes 36..63 write the 100..127 pad, never read).
#define CAND_STORE(C0, C1) { cbuf[lane] = (C0); cbuf[64 + lane] = (C1); }

// RES(v2f) = U[e0/e1,:] . cand. 25 uniform ds_read_b128 broadcasts + 100
// v_pk_fma_f32 (natural (k,k+1) pairing: no splat, no op_sel needed).
#define MATVEC_READ(RES)                                                \
    {                                                                   \
        v2f A0 = {0.f, 0.f}, A1 = {0.f, 0.f};                           \
        v2f A2 = {0.f, 0.f}, A3 = {0.f, 0.f};                           \
        _Pragma("unroll")                                               \
        for (int j = 0; j < 25; ++j) {                                  \
            float4 cc = cbuf4[j];                                       \
            v2f clo = {cc.x, cc.y};                                     \
            v2f chi = {cc.z, cc.w};                                     \
            A0 = __builtin_elementwise_fma(UE0[2 * j],     clo, A0);    \
            A1 = __builtin_elementwise_fma(UE0[2 * j + 1], chi, A1);    \
            A2 = __builtin_elementwise_fma(UE1[2 * j],     clo, A2);    \
            A3 = __builtin_elementwise_fma(UE1[2 * j + 1], chi, A3);    \
        }                                                               \
        v2f sA = A0 + A1, sB = A2 + A3;                                 \
        RES.x = sA.x + sA.y;                                            \
        RES.y = sB.x + sB.y;                                            \
    }

__global__ __attribute__((amdgpu_waves_per_eu(1, 1))) __launch_bounds__(64)
void entnet_scan(
    const float* __restrict__ enc,    // [8192*100]
    const float* __restrict__ sWp,    // [8192*100]
    const float* __restrict__ kg,     // [8192*20]
    const float* __restrict__ keys,   // [20*100]
    const float* __restrict__ U,      // [100*100]
    const float* __restrict__ V,      // [100*100]
    const float* __restrict__ paPtr,
    float* __restrict__ out)          // [32*20*100]
{
    __shared__ float4 cbuf4[32];      // 128 floats: cand broadcast buffer
    float* cbuf = (float*)cbuf4;
    const int lane = threadIdx.x;
    // XCD swizzle: XCD = blockIdx%8 serves b in {4*xcd .. 4*xcd+3}
    const int xcd = blockIdx.x & 7;
    const int gg  = blockIdx.x >> 3;          // 0..79
    const int b = xcd * 4 + gg / 20;
    const int m = gg % 20;
    const bool hi = (lane < 36);
    const float h = hi ? 1.f : 0.f;
    const int e0 = lane;
    const int e1 = hi ? (64 + lane) : 99;
    const float pa = paPtr[0];

    // U rows e0/e1 as (k,k+1) v2f pairs: UE0[j] = {U[e0][2j], U[e0][2j+1]}
    v2f UE0[50], UE1[50];
    {
        const float4* u0 = (const float4*)(U + e0 * 100);
        const float4* u1 = (const float4*)(U + e1 * 100);
        #pragma unroll
        for (int k = 0; k < 25; ++k) {
            float4 a = u0[k], c = u1[k];
            UE0[2 * k]     = (v2f){a.x, a.y};
            UE0[2 * k + 1] = (v2f){a.z, a.w};
            UE1[2 * k]     = (v2f){c.x, c.y};
            UE1[2 * k + 1] = (v2f){c.z, c.w};
        }
    }

    float kv0 = 0.f, kv1 = 0.f;
    {
        const float4* km = (const float4*)(keys + m * 100);
        const float4* v0 = (const float4*)(V + e0 * 100);
        const float4* v1 = (const float4*)(V + e1 * 100);
        #pragma unroll
        for (int k = 0; k < 25; ++k) {
            float4 kk = km[k], a = v0[k], c = v1[k];
            kv0 += a.x * kk.x + a.y * kk.y + a.z * kk.z + a.w * kk.w;
            kv1 += c.x * kk.x + c.y * kk.y + c.z * kk.z + c.w * kk.w;
        }
    }
    const float k0 = keys[m * 100 + e0];
    const float k1 = h * keys[m * 100 + e1];
    float nm0 = k0, nm1 = k1;        // unnormalized mem; true mem = rn*nm

    v2f P;                            // P = U . nm (register recurrence)
    CAND_STORE(k0, k1);
    MATVEC_READ(P);

    float nq = k0 * k0 + k1 * k1;     // ||mem_0||^2
    DPP6(nq)
    float nsq = lane63(nq);
    float rn = 1.f;

    const float* encRow = enc + (size_t)b * 25600;
    const float* sWRow  = sWp + (size_t)b * 25600;
    const float* kgRow  = kg + (size_t)b * 5120 + m;

    float sw0 = sWRow[e0], sw1 = sWRow[e1];
    float g;
    {
        const float sv0 = encRow[e0], sv1 = encRow[e1];
        const float kg0 = kgRow[0];
        float q1 = sv0 * nm0 + sv1 * nm1;
        DPP6(q1)
        const float Q1 = lane63(q1);
        g = 1.f / (1.f + __expf(-(Q1 + kg0)));   // rn == 1 at t=0
    }

    for (int step = 0; step < 256; ++step) {
        const int nxt = (step < 255 ? step + 1 : 255);
        const float nsv0 = encRow[nxt * 100 + e0], nsv1 = encRow[nxt * 100 + e1];
        const float nsw0 = sWRow[nxt * 100 + e0], nsw1 = sWRow[nxt * 100 + e1];
        const float nkg  = kgRow[nxt * 20];

        // critical path: P -> x -> cand -> LDS round-trip matvec -> P'
        const float x0 = rn * P.x + kv0 + sw0;
        const float x1 = rn * P.y + kv1 + sw1;
        float c0 = (x0 >= 0.f) ? x0 : pa * x0;
        float c1 = (x1 >= 0.f) ? x1 : pa * x1;
        c1 *= h;

        CAND_STORE(c0, c1);           // issue early: LDS latency hides under DPP

        // off-path norm partials (overlap LDS round-trip)
        float q3 = nm0 * c0 + nm1 * c1;             // nm . cand
        float p4 = c0 * c0 + c1 * c1;               // cand . cand
        #define RND2(C) q3 = dpp_add_f<C>(q3); p4 = dpp_add_f<C>(p4);
        RND2(0x111) RND2(0x112) RND2(0x114) RND2(0x118) RND2(0x142) RND2(0x143)
        #undef RND2

        v2f Q;
        MATVEC_READ(Q);

        const float Q3 = lane63(q3);
        const float P4 = lane63(p4);
        const float n2 = nsq + 2.f * (g * rn) * Q3 + g * g * P4;
        const float rnn = rsqrtf(n2);               // rn_{t+1}
        nsq = 1.f;

        nm0 = rn * nm0 + g * c0;
        nm1 = rn * nm1 + g * c1;
        P.x = rn * P.x + g * Q.x;
        P.y = rn * P.y + g * Q.y;

        // gate for step t+1 (overlaps next iteration's front)
        float q1 = nsv0 * nm0 + nsv1 * nm1;
        DPP6(q1)
        const float Q1 = lane63(q1);
        g = 1.f / (1.f + __expf(-(rnn * Q1 + nkg)));

        rn = rnn;
        sw0 = nsw0; sw1 = nsw1;
    }
    float* orow = out + (size_t)(b * 20 + m) * 100;
    orow[e0] = nm0 * rn;
    if (hi) orow[e1] = nm1 * rn;
}

extern "C" void kernel_launch(void* const* d_in, const int* in_sizes, int n_in,
                              void* d_out, int out_size, void* d_ws, size_t ws_size,
                              hipStream_t stream) {
    const float* batch = (const float*)d_in[0];
    const float* encm  = (const float*)d_in[1];
    const float* keys  = (const float*)d_in[2];
    const float* U     = (const float*)d_in[3];
    const float* V     = (const float*)d_in[4];
    const float* W     = (const float*)d_in[5];
    const float* pa    = (const float*)d_in[6];
    float* out = (float*)d_out;

    float* enc = (float*)d_ws;          // 819200 floats
    float* sWp = enc + 819200;          // 819200 floats
    float* kgb = sWp + 819200;          // 163840 floats
    float* T   = kgb + 163840;          // 12800 floats

    encode_k<<<1600, 256, 0, stream>>>(batch, encm, enc);
    prep_k<<<100, 128, 0, stream>>>(W, keys, T);
    project_k<<<2048, 128, 0, stream>>>(enc, T, sWp, kgb);
    entnet_scan<<<640, 64, 0, stream>>>(enc, sWp, kgb, keys, U, V, pa, out);
}